// Round 6
// baseline (435.744 us; speedup 1.0000x reference)
//
#include <hip/hip_runtime.h>

// ---------------------------------------------------------------------------
// DoubleLayeredEncoder: 2-layer GCN + PReLU + half-sum. N=100k, E=1.6M.
// R6: de-fuse ell/gemm1 (R5 co-schedule regressed); fix 32-way LDS bank
// conflict in gemm1 staging (lane-fast row map); split-row ELL build
// (A fills bottom, B fills top; independent counters halve atomic contention;
// 4 edges/thread for MLP). Keep R5's g1g2 / g2h fusions (h1, f never in HBM).
//
// Pipeline: memset(cntA|cntB) -> k_gemm1 -> k_ell -> k_dinv -> k_g1g2 -> k_g2h
// ---------------------------------------------------------------------------

#define ELL_CAP 64

__device__ __forceinline__ unsigned bf16rne(float x) {
    unsigned u = __float_as_uint(x);
    return (u + 0x7FFFu + ((u >> 16) & 1u)) >> 16;
}
__device__ __forceinline__ unsigned pack2bf(float a, float b) {
    return bf16rne(a) | (bf16rne(b) << 16);
}

// ---- ELL build: 4 edges/thread, split rows (2 edges -> bottom, 2 -> top) ---
__global__ __launch_bounds__(256) void k_ell(const int4* __restrict__ src4,
                                             const int4* __restrict__ dst4,
                                             const int4* __restrict__ et4,
                                             const float4* __restrict__ w4,
                                             int* __restrict__ cntA,
                                             int* __restrict__ cntB,
                                             int2* __restrict__ ell, int Equart) {
    int idx = blockIdx.x * 256 + threadIdx.x;
    if (idx >= Equart) return;
    int4 s = src4[idx];
    int4 d = dst4[idx];
    int4 tt = et4[idx];
    float4 w = w4[idx];
    int p0 = atomicAdd(&cntA[d.x], 1);
    int p1 = atomicAdd(&cntA[d.y], 1);
    int p2 = atomicAdd(&cntB[d.z], 1);
    int p3 = atomicAdd(&cntB[d.w], 1);
    if (p0 < ELL_CAP) ell[d.x * ELL_CAP + p0] = make_int2(s.x | (tt.x << 24), __float_as_int(w.x));
    if (p1 < ELL_CAP) ell[d.y * ELL_CAP + p1] = make_int2(s.y | (tt.y << 24), __float_as_int(w.y));
    if (p2 < ELL_CAP) ell[d.z * ELL_CAP + (ELL_CAP - 1) - p2] = make_int2(s.z | (tt.z << 24), __float_as_int(w.z));
    if (p3 < ELL_CAP) ell[d.w * ELL_CAP + (ELL_CAP - 1) - p3] = make_int2(s.w | (tt.w << 24), __float_as_int(w.w));
}

// ---- weighted degrees + rsqrt, 16 lanes/node ------------------------------
__global__ __launch_bounds__(256) void k_dinv(const int* __restrict__ cntA,
                                              const int* __restrict__ cntB,
                                              const int2* __restrict__ ell,
                                              float* __restrict__ dinv1,
                                              float* __restrict__ dinv2, int n) {
    int t = threadIdx.x;
    int d = blockIdx.x * 16 + (t >> 4);
    int g = t & 15;
    float s1 = 0.f, s2 = 0.f;
    if (d < n) {
        int lenA = min(cntA[d], ELL_CAP);
        int lenB = min(cntB[d], ELL_CAP - lenA);
        int len = lenA + lenB;
        int pad = ELL_CAP - len;
        const int2* row = ell + (size_t)d * ELL_CAP;
        for (int kk = g; kk < len; kk += 16) {
            int slot = kk + (kk >= lenA ? pad : 0);
            int2 e = row[slot];
            s1 += __int_as_float(e.y);
            s2 += (float)(((unsigned)e.x) >> 24);
        }
    }
#pragma unroll
    for (int o = 8; o >= 1; o >>= 1) {
        s1 += __shfl_xor(s1, o, 16);
        s2 += __shfl_xor(s2, o, 16);
    }
    if (d < n && g == 0) {
        dinv1[d] = rsqrtf(1.0f + s1);
        dinv2[d] = rsqrtf(1.0f + s2);
    }
}

// ---- gemm1: xb1 = bf16(x @ W1) UNSCALED. 32 rows/block, W from L2. --------
// Staging uses lane-fast row mapping: conflict-free LDS writes.
__global__ __launch_bounds__(256) void k_gemm1(const float* __restrict__ x,
                                               const float* __restrict__ W,
                                               unsigned* __restrict__ xb1, int n) {
    __shared__ float xs[128 * 32];   // [k][r], 16 KB
    int t = threadIdx.x;
    int row0 = blockIdx.x * 32;
    const float4* x4 = (const float4*)x;
#pragma unroll
    for (int i = 0; i < 4; i++) {
        int q = t + 256 * i;            // 0..1023
        int r = q & 31;                 // lane-fast row -> consecutive banks
        int c4 = (q >> 5) << 2;         // 0..124
        int row = row0 + r;
        float4 v = make_float4(0.f, 0.f, 0.f, 0.f);
        if (row < n) v = x4[row * 32 + (c4 >> 2)];
        xs[(c4 + 0) * 32 + r] = v.x;
        xs[(c4 + 1) * 32 + r] = v.y;
        xs[(c4 + 2) * 32 + r] = v.z;
        xs[(c4 + 3) * 32 + r] = v.w;
    }
    __syncthreads();

    int c4 = (t & 31) << 2;
    int r4 = (t >> 5) << 2;
    const float4* W4 = (const float4*)W;
    float acc[4][4] = {};
#pragma unroll 8
    for (int k = 0; k < 128; k++) {
        float4 xv = *(const float4*)&xs[k * 32 + r4];   // broadcast, free
        float4 wv = W4[k * 32 + (c4 >> 2)];             // coalesced, L2-hot
        acc[0][0] += xv.x * wv.x; acc[0][1] += xv.x * wv.y; acc[0][2] += xv.x * wv.z; acc[0][3] += xv.x * wv.w;
        acc[1][0] += xv.y * wv.x; acc[1][1] += xv.y * wv.y; acc[1][2] += xv.y * wv.z; acc[1][3] += xv.y * wv.w;
        acc[2][0] += xv.z * wv.x; acc[2][1] += xv.z * wv.y; acc[2][2] += xv.z * wv.z; acc[2][3] += xv.z * wv.w;
        acc[3][0] += xv.w * wv.x; acc[3][1] += xv.w * wv.y; acc[3][2] += xv.w * wv.z; acc[3][3] += xv.w * wv.w;
    }
#pragma unroll
    for (int i = 0; i < 4; i++) {
        int row = row0 + r4 + i;
        if (row < n) {
            uint2 o = make_uint2(pack2bf(acc[i][0], acc[i][1]),
                                 pack2bf(acc[i][2], acc[i][3]));
            ((uint2*)xb1)[row * 32 + (c4 >> 2)] = o;
        }
    }
}

// ---- gather1 (+dinv, bias, PReLU) fused with gemm2 -> xb2 -----------------
// 8 nodes/block, 32 lanes/node. W2 bf16 in LDS; h1 tile in LDS only.
__global__ __launch_bounds__(256) void k_g1g2(const int* __restrict__ cntA,
                                              const int* __restrict__ cntB,
                                              const int2* __restrict__ ell,
                                              const unsigned* __restrict__ xb1,
                                              const float* __restrict__ dinv1,
                                              const float* __restrict__ b,
                                              const float* __restrict__ alpha,
                                              const float* __restrict__ W2,
                                              unsigned* __restrict__ xb2, int n) {
    __shared__ unsigned W2s[128 * 32];   // bf16-packed col pairs, 16 KB
    __shared__ float hs[8 * 128];        // h1 tile, 4 KB
    int t = threadIdx.x;

    const float2* W22 = (const float2*)W2;
#pragma unroll
    for (int i = 0; i < 16; i++) {
        int idx = t + 256 * i;           // 0..4095
        float2 v = W22[idx];
        W2s[idx] = pack2bf(v.x, v.y);
    }

    int nl = t >> 5;                     // node slot 0..7
    int g = t & 31;
    int d = blockIdx.x * 8 + nl;
    bool active = d < n;
    int lenA = 0, lenB = 0;
    if (active) {
        lenA = min(cntA[d], ELL_CAP);
        lenB = min(cntB[d], ELL_CAP - lenA);
    }
    int len = lenA + lenB;
    int pad = ELL_CAP - len;
    const int2* row = ell + (size_t)d * ELL_CAP;
    const uint2* x2 = (const uint2*)xb1;

    float a0 = 0.f, a1v_ = 0.f, a2v_ = 0.f, a3 = 0.f;
    for (int k0 = 0; k0 < len; k0 += 32) {
        int kk = k0 + g;
        int2 ent = make_int2(0, 0);
        float cf = 0.f;
        if (kk < len) {
            int slot = kk + (kk >= lenA ? pad : 0);
            ent = row[slot];
            cf = __int_as_float(ent.y) * dinv1[ent.x & 0xFFFFFF];  // w*dinv1[src]
        }
        int m = min(32, len - k0);
        for (int j = 0; j < m; j++) {
            int pej = __shfl(ent.x, j, 32);
            float cj = __shfl(cf, j, 32);
            int s = pej & 0xFFFFFF;
            uint2 q = x2[s * 32 + g];
            a0 += __uint_as_float(q.x << 16) * cj;
            a1v_ += __uint_as_float(q.x & 0xFFFF0000u) * cj;
            a2v_ += __uint_as_float(q.y << 16) * cj;
            a3 += __uint_as_float(q.y & 0xFFFF0000u) * cj;
        }
    }

    if (active) {
        float di = dinv1[d];
        uint2 sq = x2[d * 32 + g];
        float s0 = __uint_as_float(sq.x << 16);
        float s1 = __uint_as_float(sq.x & 0xFFFF0000u);
        float s2 = __uint_as_float(sq.y << 16);
        float s3 = __uint_as_float(sq.y & 0xFFFF0000u);
        int c4 = g << 2;
        float4 bv = *(const float4*)&b[c4];
        float4 av = *(const float4*)&alpha[c4];
        float v0 = di * (a0 + s0 * di) + bv.x; v0 = v0 >= 0.f ? v0 : av.x * v0;
        float v1 = di * (a1v_ + s1 * di) + bv.y; v1 = v1 >= 0.f ? v1 : av.y * v1;
        float v2 = di * (a2v_ + s2 * di) + bv.z; v2 = v2 >= 0.f ? v2 : av.z * v2;
        float v3 = di * (a3 + s3 * di) + bv.w; v3 = v3 >= 0.f ? v3 : av.w * v3;
        *(float4*)&hs[nl * 128 + c4] = make_float4(v0, v1, v2, v3);
    }
    __syncthreads();

    float o0 = 0.f, o1 = 0.f;
#pragma unroll 4
    for (int k = 0; k < 128; k++) {
        float hv = hs[nl * 128 + k];     // broadcast
        unsigned pw = W2s[k * 32 + g];   // conflict-free
        o0 += hv * __uint_as_float(pw << 16);
        o1 += hv * __uint_as_float(pw & 0xFFFF0000u);
    }
    if (active) xb2[d * 32 + g] = pack2bf(o0, o1);
}

// ---- gather2 (+dinv, bias, PReLU) fused with half-sum readout -------------
// 8 node-pairs (j, j+half)/block, 16 lanes/node. Skip etype==0 edges.
__global__ __launch_bounds__(256) void k_g2h(const int* __restrict__ cntA,
                                             const int* __restrict__ cntB,
                                             const int2* __restrict__ ell,
                                             const unsigned* __restrict__ xb2,
                                             const float* __restrict__ dinv2,
                                             const float* __restrict__ b,
                                             const float* __restrict__ alpha,
                                             float* __restrict__ out, int half) {
    __shared__ float fs[8 * 64];         // 2 KB
    int t = threadIdx.x;
    int slot = t >> 4;                   // 0..15
    int g = t & 15;
    int base = blockIdx.x * 8;
    int j = base + ((slot < 8) ? slot : (slot - 8));
    int d = (slot < 8) ? j : (j + half);
    bool active = j < half;
    int lenA = 0, lenB = 0;
    if (active) {
        lenA = min(cntA[d], ELL_CAP);
        lenB = min(cntB[d], ELL_CAP - lenA);
    }
    int len = lenA + lenB;
    int pad = ELL_CAP - len;
    const int2* row = ell + (size_t)d * ELL_CAP;
    const uint2* x2 = (const uint2*)xb2;

    float a0 = 0.f, a1v_ = 0.f, a2v_ = 0.f, a3 = 0.f;
    for (int k0 = 0; k0 < len; k0 += 16) {
        int kk = k0 + g;
        int2 ent = make_int2(0, 0);
        float cf = 0.f;
        if (kk < len) {
            int sl = kk + (kk >= lenA ? pad : 0);
            ent = row[sl];
            int tt = ((unsigned)ent.x) >> 24;
            if (tt) cf = (float)tt * dinv2[ent.x & 0xFFFFFF];   // et*dinv2[src]
        }
        int m = min(16, len - k0);
        for (int jj = 0; jj < m; jj++) {
            int pej = __shfl(ent.x, jj, 16);
            float cj = __shfl(cf, jj, 16);
            if (cj != 0.f) {
                int s = pej & 0xFFFFFF;
                uint2 q = x2[s * 16 + g];
                a0 += __uint_as_float(q.x << 16) * cj;
                a1v_ += __uint_as_float(q.x & 0xFFFF0000u) * cj;
                a2v_ += __uint_as_float(q.y << 16) * cj;
                a3 += __uint_as_float(q.y & 0xFFFF0000u) * cj;
            }
        }
    }

    float f0 = 0.f, f1 = 0.f, f2 = 0.f, f3 = 0.f;
    if (active) {
        float di = dinv2[d];
        uint2 sq = x2[d * 16 + g];
        float s0 = __uint_as_float(sq.x << 16);
        float s1 = __uint_as_float(sq.x & 0xFFFF0000u);
        float s2 = __uint_as_float(sq.y << 16);
        float s3 = __uint_as_float(sq.y & 0xFFFF0000u);
        int c4 = g << 2;
        float4 bv = *(const float4*)&b[c4];
        float4 av = *(const float4*)&alpha[c4];
        f0 = di * (a0 + s0 * di) + bv.x; f0 = f0 >= 0.f ? f0 : av.x * f0;
        f1 = di * (a1v_ + s1 * di) + bv.y; f1 = f1 >= 0.f ? f1 : av.y * f1;
        f2 = di * (a2v_ + s2 * di) + bv.z; f2 = f2 >= 0.f ? f2 : av.z * f2;
        f3 = di * (a3 + s3 * di) + bv.w; f3 = f3 >= 0.f ? f3 : av.w * f3;
    }
    if (slot >= 8)
        *(float4*)&fs[(slot - 8) * 64 + (g << 2)] = make_float4(f0, f1, f2, f3);
    __syncthreads();
    if (slot < 8 && active) {
        float4 p = *(const float4*)&fs[slot * 64 + (g << 2)];
        ((float4*)out)[j * 16 + g] = make_float4(0.5f * (f0 + p.x), 0.5f * (f1 + p.y),
                                                 0.5f * (f2 + p.z), 0.5f * (f3 + p.w));
    }
}

extern "C" void kernel_launch(void* const* d_in, const int* in_sizes, int n_in,
                              void* d_out, int out_size, void* d_ws, size_t ws_size,
                              hipStream_t stream) {
    const float* x  = (const float*)d_in[0];
    const int*   ei = (const int*)d_in[1];
    const float* ew = (const float*)d_in[2];
    const int*   et = (const int*)d_in[3];
    const float* W1 = (const float*)d_in[4];
    const float* b1 = (const float*)d_in[5];
    const float* a1 = (const float*)d_in[6];
    const float* W2 = (const float*)d_in[7];
    const float* b2 = (const float*)d_in[8];
    const float* a2 = (const float*)d_in[9];

    const int N = in_sizes[0] / 128;   // 100000
    const int E = in_sizes[1] / 2;     // 1600000
    const int* src = ei;
    const int* dst = ei + E;

    // Workspace (4-byte words), ~91 MB:
    //   dinv1 N | dinv2 N | xb1 64N | xb2 32N | cntA N | cntB N | ell 128N
    float*    ws    = (float*)d_ws;
    float*    dinv1 = ws;
    float*    dinv2 = dinv1 + N;
    unsigned* xb1   = (unsigned*)(dinv2 + N);
    unsigned* xb2   = xb1 + (size_t)N * 64;
    int*      cntA  = (int*)(xb2 + (size_t)N * 32);
    int*      cntB  = cntA + N;
    int2*     ell   = (int2*)(cntB + N);

    const int Equart = E / 4;                      // 400000

    hipMemsetAsync(cntA, 0, (size_t)2 * N * sizeof(int), stream);

    k_gemm1<<<(N + 31) / 32, 256, 0, stream>>>(x, W1, xb1, N);

    k_ell<<<(Equart + 255) / 256, 256, 0, stream>>>(
        (const int4*)src, (const int4*)dst, (const int4*)et, (const float4*)ew,
        cntA, cntB, ell, Equart);

    k_dinv<<<(N + 15) / 16, 256, 0, stream>>>(cntA, cntB, ell, dinv1, dinv2, N);

    k_g1g2<<<(N + 7) / 8, 256, 0, stream>>>(cntA, cntB, ell, xb1, dinv1, b1, a1,
                                            W2, xb2, N);

    k_g2h<<<(N / 2 + 7) / 8, 256, 0, stream>>>(cntA, cntB, ell, xb2, dinv2, b2, a2,
                                               (float*)d_out, N / 2);
}